// Round 4
// baseline (509.379 us; speedup 1.0000x reference)
//
#include <hip/hip_runtime.h>
#include <hip/hip_bf16.h>

#define DIM 128

typedef __attribute__((ext_vector_type(8))) short bf16x8;
typedef __attribute__((ext_vector_type(4))) float f32x4;
typedef __attribute__((ext_vector_type(4))) short short4v;

__device__ inline unsigned short f2bf(float f) {
  union { float f; unsigned u; } v; v.f = f;
  return (unsigned short)((v.u + 0x7FFFu + ((v.u >> 16) & 1u)) >> 16);
}
__device__ inline float lo_f(unsigned u) {  // float from low bf16 of packed pair
  union { unsigned u; float f; } v; v.u = u << 16; return v.f;
}
__device__ inline float hi_f(unsigned u) {  // float from high bf16
  union { unsigned u; float f; } v; v.u = u & 0xFFFF0000u; return v.f;
}

// ---------------------------------------------------------------------------
// K1: histogram of dst degrees
// ---------------------------------------------------------------------------
__global__ __launch_bounds__(256) void hist_kernel(
    const int* __restrict__ ei, int* __restrict__ cnt, int E) {
  int e = blockIdx.x * blockDim.x + threadIdx.x;
  if (e >= E) return;
  atomicAdd(&cnt[ei[E + e]], 1);
}

// ---------------------------------------------------------------------------
// K2a/b/c: exclusive prefix scan of cnt -> off
// ---------------------------------------------------------------------------
__global__ __launch_bounds__(256) void scan1_kernel(
    const int* __restrict__ cnt, int* __restrict__ scratch,
    int* __restrict__ bsum, int n) {
  __shared__ int tmp[256];
  int gid = blockIdx.x * 256 + threadIdx.x;
  int v = (gid < n) ? cnt[gid] : 0;
  tmp[threadIdx.x] = v;
  __syncthreads();
  for (int off = 1; off < 256; off <<= 1) {
    int t = (threadIdx.x >= off) ? tmp[threadIdx.x - off] : 0;
    __syncthreads();
    tmp[threadIdx.x] += t;
    __syncthreads();
  }
  if (gid < n) scratch[gid] = tmp[threadIdx.x] - v;
  if (threadIdx.x == 255) bsum[blockIdx.x] = tmp[255];
}

__global__ __launch_bounds__(256) void scan2_kernel(int* __restrict__ bsum, int nb) {
  __shared__ int tmp[256];
  int v = (threadIdx.x < nb) ? bsum[threadIdx.x] : 0;
  tmp[threadIdx.x] = v;
  __syncthreads();
  for (int off = 1; off < 256; off <<= 1) {
    int t = (threadIdx.x >= off) ? tmp[threadIdx.x - off] : 0;
    __syncthreads();
    tmp[threadIdx.x] += t;
    __syncthreads();
  }
  if (threadIdx.x < nb) bsum[threadIdx.x] = tmp[threadIdx.x] - v;
}

__global__ __launch_bounds__(256) void scan3_kernel(
    const int* __restrict__ scratch, const int* __restrict__ bsum,
    int* __restrict__ off, int n) {
  int gid = blockIdx.x * 256 + threadIdx.x;
  if (gid < n) off[gid] = scratch[gid] + bsum[blockIdx.x];
}

// ---------------------------------------------------------------------------
// K3: fill CSR buckets
// ---------------------------------------------------------------------------
__global__ __launch_bounds__(256) void fill_kernel(
    const int* __restrict__ ei, const int* __restrict__ off,
    int* __restrict__ fillc, int* __restrict__ bucket, int E) {
  int e = blockIdx.x * blockDim.x + threadIdx.x;
  if (e >= E) return;
  int src = ei[e];
  int dst = ei[E + e];
  int pos = off[dst] + atomicAdd(&fillc[dst], 1);
  bucket[pos] = src;
}

// ---------------------------------------------------------------------------
// K4: cast x -> bf16 into the x-half of A.  A layout: [mpad][256] bf16,
// k<128 = agg (written by agg_kernel), k>=128 = x.
// ---------------------------------------------------------------------------
__global__ __launch_bounds__(256) void xcast_kernel(
    const float* __restrict__ x, short* __restrict__ A, int nnodes, int mpad) {
  int t = blockIdx.x * 256 + threadIdx.x;
  int node = t >> 5;
  if (node >= mpad) return;
  int c = (t & 31) * 4;
  short4v o = (short4v){0, 0, 0, 0};
  if (node < nnodes) {
    float4 v = *reinterpret_cast<const float4*>(x + (size_t)node * DIM + c);
    o.x = (short)f2bf(v.x); o.y = (short)f2bf(v.y);
    o.z = (short)f2bf(v.z); o.w = (short)f2bf(v.w);
  }
  *reinterpret_cast<short4v*>(A + (size_t)node * 256 + 128 + c) = o;
}

// ---------------------------------------------------------------------------
// K5: mean-aggregation, one wave per node; gathers bf16 x-rows from A's
// x-half (256B/row coalesced, 4-deep MLP), writes bf16 agg into A's agg-half.
// ---------------------------------------------------------------------------
__global__ __launch_bounds__(256) void agg_kernel(
    const int* __restrict__ cnt, const int* __restrict__ off,
    const int* __restrict__ bucket, short* __restrict__ A,
    int nnodes, int mpad) {
  const int wid = (blockIdx.x * 256 + threadIdx.x) >> 6;
  const int lane = threadIdx.x & 63;
  if (wid >= mpad) return;
  unsigned* dst = reinterpret_cast<unsigned*>(A + (size_t)wid * 256) + lane;
  if (wid >= nnodes) { *dst = 0u; return; }
  const int deg  = __builtin_amdgcn_readfirstlane(cnt[wid]);
  const int base = __builtin_amdgcn_readfirstlane(off[wid]);
  const unsigned* xs = reinterpret_cast<const unsigned*>(A) + 64 + lane;  // +64 uints = x-half

  float a0 = 0.f, b0 = 0.f, a1 = 0.f, b1 = 0.f;
  float a2 = 0.f, b2 = 0.f, a3 = 0.f, b3 = 0.f;
  int j = 0;
  for (; j + 3 < deg; j += 4) {
    const int s0 = __builtin_amdgcn_readfirstlane(bucket[base + j]);
    const int s1 = __builtin_amdgcn_readfirstlane(bucket[base + j + 1]);
    const int s2 = __builtin_amdgcn_readfirstlane(bucket[base + j + 2]);
    const int s3 = __builtin_amdgcn_readfirstlane(bucket[base + j + 3]);
    unsigned u0 = xs[(size_t)s0 * 128];
    unsigned u1 = xs[(size_t)s1 * 128];
    unsigned u2 = xs[(size_t)s2 * 128];
    unsigned u3 = xs[(size_t)s3 * 128];
    a0 += lo_f(u0); b0 += hi_f(u0);
    a1 += lo_f(u1); b1 += hi_f(u1);
    a2 += lo_f(u2); b2 += hi_f(u2);
    a3 += lo_f(u3); b3 += hi_f(u3);
  }
  for (; j < deg; ++j) {
    const int s0 = __builtin_amdgcn_readfirstlane(bucket[base + j]);
    unsigned u0 = xs[(size_t)s0 * 128];
    a0 += lo_f(u0); b0 += hi_f(u0);
  }
  const float r = 1.0f / fmaxf((float)deg, 1.0f);
  const float av = (a0 + a1 + a2 + a3) * r;
  const float bv = (b0 + b1 + b2 + b3) * r;
  *dst = (unsigned)f2bf(av) | ((unsigned)f2bf(bv) << 16);
}

// ---------------------------------------------------------------------------
// K6: pack B = [[Wl];[Wr]] (256x128) into MFMA fragment order:
// frag f=(ks*8+nt): lane holds B[ks*32+(lane>>4)*8 + j][nt*16+(lane&15)], j=0..7
// ---------------------------------------------------------------------------
__global__ __launch_bounds__(256) void bpack_kernel(
    const float* __restrict__ Wl, const float* __restrict__ Wr,
    short* __restrict__ Bpack) {
  int t = blockIdx.x * 256 + threadIdx.x;
  if (t >= 4096) return;
  int lane = t & 63, nt = (t >> 6) & 7, ks = t >> 9;
  int c = nt * 16 + (lane & 15);
  int kb = ks * 32 + ((lane >> 4) << 3);
  bf16x8 o;
#pragma unroll
  for (int j = 0; j < 8; ++j) {
    int k = kb + j;
    float v = (k < DIM) ? Wl[k * DIM + c] : Wr[(k - DIM) * DIM + c];
    o[j] = (short)f2bf(v);
  }
  reinterpret_cast<bf16x8*>(Bpack)[(ks * 8 + nt) * 64 + lane] = o;
}

// ---------------------------------------------------------------------------
// K7: MFMA GEMM + fused bias/relu/row-masked column-sum.
// Block = 4 waves, M-tile = 64 rows; wave w owns rows 16w..16w+15, all 128 h.
// A staged in LDS with XOR swizzle (row stride 512B -> bank collision w/o it).
// B fragments read from L2-resident Bpack (16B/lane, coalesced).
// C/D layout (m89-verified): col=lane&15, row=(lane>>4)*4+reg.
// ---------------------------------------------------------------------------
__global__ __launch_bounds__(256) void mfma_kernel(
    const short* __restrict__ A, const short* __restrict__ Bpack,
    const float* __restrict__ bl, float* __restrict__ partial, int nnodes) {
  __shared__ short a_lds[64 * 256];
  const int tid = threadIdx.x;
  const int wave = tid >> 6, lane = tid & 63;
  const int mt = blockIdx.x;
  const size_t abase = (size_t)mt * 64 * 256;

#pragma unroll
  for (int r = 0; r < 8; ++r) {
    int i = tid + 256 * r;
    int row = i >> 5, kc = i & 31;
    bf16x8 v = *reinterpret_cast<const bf16x8*>(A + abase + row * 256 + kc * 8);
    int byte = (row * 512 + kc * 16) ^ ((row & 7) << 4);
    *reinterpret_cast<bf16x8*>(reinterpret_cast<char*>(a_lds) + byte) = v;
  }
  __syncthreads();

  f32x4 acc[8];
#pragma unroll
  for (int nt = 0; nt < 8; ++nt) acc[nt] = (f32x4){0.f, 0.f, 0.f, 0.f};

  const int arow = wave * 16 + (lane & 15);
  const int kgrp = lane >> 4;
  const bf16x8* Bp = reinterpret_cast<const bf16x8*>(Bpack);

#pragma unroll
  for (int ks = 0; ks < 8; ++ks) {
    int byte = (arow * 512 + (ks * 32 + kgrp * 8) * 2) ^ ((arow & 7) << 4);
    bf16x8 a = *reinterpret_cast<const bf16x8*>(reinterpret_cast<char*>(a_lds) + byte);
#pragma unroll
    for (int nt = 0; nt < 8; ++nt) {
      bf16x8 b = Bp[(ks * 8 + nt) * 64 + lane];
      acc[nt] = __builtin_amdgcn_mfma_f32_16x16x32_bf16(a, b, acc[nt], 0, 0, 0);
    }
  }

  const int col16 = lane & 15;
  const int rowbase = mt * 64 + wave * 16 + kgrp * 4;
#pragma unroll
  for (int nt = 0; nt < 8; ++nt) {
    const int c = nt * 16 + col16;
    const float bb = bl[c];
    float s = 0.f;
#pragma unroll
    for (int rg = 0; rg < 4; ++rg) {
      float v = fmaxf(acc[nt][rg] + bb, 0.f);
      s += (rowbase + rg < nnodes) ? v : 0.f;
    }
    s += __shfl_xor(s, 16);
    s += __shfl_xor(s, 32);
    if (kgrp == 0) partial[((size_t)mt * 4 + wave) * DIM + c] = s;
  }
}

// ---------------------------------------------------------------------------
// K8: sum partial rows, dot with W_out
// ---------------------------------------------------------------------------
__global__ __launch_bounds__(256) void final_kernel(
    const float* __restrict__ partial, int nrows,
    const float* __restrict__ Wout, const float* __restrict__ bout,
    float* __restrict__ out, int nnodes) {
  __shared__ float colsum[128];
  int t = threadIdx.x;
  int c = t & 127, half = t >> 7;
  float s = 0.f;
  for (int r = half; r < nrows; r += 2) s += partial[(size_t)r * DIM + c];
  if (half) colsum[c] = s;
  __syncthreads();
  if (!half) colsum[c] = (s + colsum[c]) * Wout[c];
  __syncthreads();
  if (t == 0) {
    float v = 0.f;
    for (int i = 0; i < 128; ++i) v += colsum[i];
    out[0] = v / (float)nnodes + bout[0];
  }
}

extern "C" void kernel_launch(void* const* d_in, const int* in_sizes, int n_in,
                              void* d_out, int out_size, void* d_ws, size_t ws_size,
                              hipStream_t stream) {
  const float* x    = (const float*)d_in[0];   // x_ligand [N,128]
  const int*   ei   = (const int*)d_in[4];     // ei_ll [2,E]
  const float* Wl   = (const float*)d_in[11];  // Wl_ll [128,128]
  const float* bl   = (const float*)d_in[12];  // bl_ll [128]
  const float* Wr   = (const float*)d_in[13];  // Wr_ll [128,128]
  const float* Wout = (const float*)d_in[14];  // W_out [128,1]
  const float* bout = (const float*)d_in[15];  // b_out [1]

  const int nnodes = in_sizes[0] / DIM;
  const int E = in_sizes[4] / 2;
  const int mtiles = (nnodes + 63) / 64;
  const int mpad = mtiles * 64;

  // ws layout: [cnt N][fillc N][off N][scratch N][bsum 256][bucket E][A mpad*256 bf16][Bpack 32768 bf16]
  // partial (mtiles*4*128 f32) aliases bucket (bucket dead after agg_kernel).
  int* cnt_i   = (int*)d_ws;
  int* fillc   = cnt_i + nnodes;
  int* off     = fillc + nnodes;
  int* scratch = off + nnodes;
  int* bsum    = scratch + nnodes;
  int* bucket  = bsum + 256;
  short* A     = (short*)(bucket + E);
  short* Bpack = A + (size_t)mpad * 256;
  float* partial = (float*)bucket;  // alias

  // zero cnt + fillc (contiguous)
  hipMemsetAsync(d_ws, 0, (size_t)(2 * nnodes) * sizeof(int), stream);

  const int eblocks = (E + 255) / 256;
  hist_kernel<<<eblocks, 256, 0, stream>>>(ei, cnt_i, E);

  const int nblocks = (nnodes + 255) / 256;
  scan1_kernel<<<nblocks, 256, 0, stream>>>(cnt_i, scratch, bsum, nnodes);
  scan2_kernel<<<1, 256, 0, stream>>>(bsum, nblocks);
  scan3_kernel<<<nblocks, 256, 0, stream>>>(scratch, bsum, off, nnodes);

  fill_kernel<<<eblocks, 256, 0, stream>>>(ei, off, fillc, bucket, E);

  bpack_kernel<<<16, 256, 0, stream>>>(Wl, Wr, Bpack);

  const int xblocks = (mpad * 32 + 255) / 256;
  xcast_kernel<<<xblocks, 256, 0, stream>>>(x, A, nnodes, mpad);

  const int ablocks = (mpad + 3) / 4;  // one wave per node
  agg_kernel<<<ablocks, 256, 0, stream>>>(cnt_i, off, bucket, A, nnodes, mpad);

  mfma_kernel<<<mtiles, 256, 0, stream>>>(A, Bpack, bl, partial, nnodes);

  final_kernel<<<1, 256, 0, stream>>>(partial, mtiles * 4, Wout, bout,
                                      (float*)d_out, nnodes);
}

// Round 5
// 167.169 us; speedup vs baseline: 3.0471x; 3.0471x over previous
//
#include <hip/hip_runtime.h>
#include <hip/hip_bf16.h>

#define DIM 128

typedef __attribute__((ext_vector_type(8))) short bf16x8;
typedef __attribute__((ext_vector_type(4))) float f32x4;
typedef __attribute__((ext_vector_type(4))) short short4v;

__device__ inline unsigned short f2bf(float f) {
  union { float f; unsigned u; } v; v.f = f;
  return (unsigned short)((v.u + 0x7FFFu + ((v.u >> 16) & 1u)) >> 16);
}
__device__ inline float lo_f(unsigned u) {
  union { unsigned u; float f; } v; v.u = u << 16; return v.f;
}
__device__ inline float hi_f(unsigned u) {
  union { unsigned u; float f; } v; v.u = u & 0xFFFF0000u; return v.f;
}

// ---------------------------------------------------------------------------
// K1: histogram of dst degrees
// ---------------------------------------------------------------------------
__global__ __launch_bounds__(256) void hist_kernel(
    const int* __restrict__ ei, int* __restrict__ cnt, int E) {
  int e = blockIdx.x * blockDim.x + threadIdx.x;
  if (e >= E) return;
  atomicAdd(&cnt[ei[E + e]], 1);
}

// ---------------------------------------------------------------------------
// K2a/b/c: exclusive prefix scan of cnt -> off
// ---------------------------------------------------------------------------
__global__ __launch_bounds__(256) void scan1_kernel(
    const int* __restrict__ cnt, int* __restrict__ scratch,
    int* __restrict__ bsum, int n) {
  __shared__ int tmp[256];
  int gid = blockIdx.x * 256 + threadIdx.x;
  int v = (gid < n) ? cnt[gid] : 0;
  tmp[threadIdx.x] = v;
  __syncthreads();
  for (int off = 1; off < 256; off <<= 1) {
    int t = (threadIdx.x >= off) ? tmp[threadIdx.x - off] : 0;
    __syncthreads();
    tmp[threadIdx.x] += t;
    __syncthreads();
  }
  if (gid < n) scratch[gid] = tmp[threadIdx.x] - v;
  if (threadIdx.x == 255) bsum[blockIdx.x] = tmp[255];
}

__global__ __launch_bounds__(256) void scan2_kernel(int* __restrict__ bsum, int nb) {
  __shared__ int tmp[256];
  int v = (threadIdx.x < nb) ? bsum[threadIdx.x] : 0;
  tmp[threadIdx.x] = v;
  __syncthreads();
  for (int off = 1; off < 256; off <<= 1) {
    int t = (threadIdx.x >= off) ? tmp[threadIdx.x - off] : 0;
    __syncthreads();
    tmp[threadIdx.x] += t;
    __syncthreads();
  }
  if (threadIdx.x < nb) bsum[threadIdx.x] = tmp[threadIdx.x] - v;
}

__global__ __launch_bounds__(256) void scan3_kernel(
    const int* __restrict__ scratch, const int* __restrict__ bsum,
    int* __restrict__ off, int n) {
  int gid = blockIdx.x * 256 + threadIdx.x;
  if (gid < n) off[gid] = scratch[gid] + bsum[blockIdx.x];
}

// ---------------------------------------------------------------------------
// K3: fill CSR buckets
// ---------------------------------------------------------------------------
__global__ __launch_bounds__(256) void fill_kernel(
    const int* __restrict__ ei, const int* __restrict__ off,
    int* __restrict__ fillc, int* __restrict__ bucket, int E) {
  int e = blockIdx.x * blockDim.x + threadIdx.x;
  if (e >= E) return;
  int src = ei[e];
  int dst = ei[E + e];
  int pos = off[dst] + atomicAdd(&fillc[dst], 1);
  bucket[pos] = src;
}

// ---------------------------------------------------------------------------
// K4: cast x -> bf16 into the x-half of A.  A layout: [mpad][256] bf16,
// k<128 = agg (written by agg_kernel), k>=128 = x.
// ---------------------------------------------------------------------------
__global__ __launch_bounds__(256) void xcast_kernel(
    const float* __restrict__ x, short* __restrict__ A, int nnodes, int mpad) {
  int t = blockIdx.x * 256 + threadIdx.x;
  int node = t >> 5;
  if (node >= mpad) return;
  int c = (t & 31) * 4;
  short4v o = (short4v){0, 0, 0, 0};
  if (node < nnodes) {
    float4 v = *reinterpret_cast<const float4*>(x + (size_t)node * DIM + c);
    o.x = (short)f2bf(v.x); o.y = (short)f2bf(v.y);
    o.z = (short)f2bf(v.z); o.w = (short)f2bf(v.w);
  }
  *reinterpret_cast<short4v*>(A + (size_t)node * 256 + 128 + c) = o;
}

// ---------------------------------------------------------------------------
// K5: mean-aggregation, one wave per node; gathers bf16 x-rows from A's
// x-half (256B/row coalesced, 4-deep MLP), writes bf16 agg into A's agg-half.
// ---------------------------------------------------------------------------
__global__ __launch_bounds__(256) void agg_kernel(
    const int* __restrict__ cnt, const int* __restrict__ off,
    const int* __restrict__ bucket, short* __restrict__ A,
    int nnodes, int mpad) {
  const int wid = (blockIdx.x * 256 + threadIdx.x) >> 6;
  const int lane = threadIdx.x & 63;
  if (wid >= mpad) return;
  unsigned* dst = reinterpret_cast<unsigned*>(A + (size_t)wid * 256) + lane;
  if (wid >= nnodes) { *dst = 0u; return; }
  const int deg  = __builtin_amdgcn_readfirstlane(cnt[wid]);
  const int base = __builtin_amdgcn_readfirstlane(off[wid]);
  const unsigned* xs = reinterpret_cast<const unsigned*>(A) + 64 + lane;

  float a0 = 0.f, b0 = 0.f, a1 = 0.f, b1 = 0.f;
  float a2 = 0.f, b2 = 0.f, a3 = 0.f, b3 = 0.f;
  int j = 0;
  for (; j + 3 < deg; j += 4) {
    const int s0 = __builtin_amdgcn_readfirstlane(bucket[base + j]);
    const int s1 = __builtin_amdgcn_readfirstlane(bucket[base + j + 1]);
    const int s2 = __builtin_amdgcn_readfirstlane(bucket[base + j + 2]);
    const int s3 = __builtin_amdgcn_readfirstlane(bucket[base + j + 3]);
    unsigned u0 = xs[(size_t)s0 * 128];
    unsigned u1 = xs[(size_t)s1 * 128];
    unsigned u2 = xs[(size_t)s2 * 128];
    unsigned u3 = xs[(size_t)s3 * 128];
    a0 += lo_f(u0); b0 += hi_f(u0);
    a1 += lo_f(u1); b1 += hi_f(u1);
    a2 += lo_f(u2); b2 += hi_f(u2);
    a3 += lo_f(u3); b3 += hi_f(u3);
  }
  for (; j < deg; ++j) {
    const int s0 = __builtin_amdgcn_readfirstlane(bucket[base + j]);
    unsigned u0 = xs[(size_t)s0 * 128];
    a0 += lo_f(u0); b0 += hi_f(u0);
  }
  const float r = 1.0f / fmaxf((float)deg, 1.0f);
  const float av = (a0 + a1 + a2 + a3) * r;
  const float bv = (b0 + b1 + b2 + b3) * r;
  *dst = (unsigned)f2bf(av) | ((unsigned)f2bf(bv) << 16);
}

// ---------------------------------------------------------------------------
// K6: pack B = [[Wl];[Wr]] (256x128) into MFMA fragment order
// ---------------------------------------------------------------------------
__global__ __launch_bounds__(256) void bpack_kernel(
    const float* __restrict__ Wl, const float* __restrict__ Wr,
    short* __restrict__ Bpack) {
  int t = blockIdx.x * 256 + threadIdx.x;
  if (t >= 4096) return;
  int lane = t & 63, nt = (t >> 6) & 7, ks = t >> 9;
  int c = nt * 16 + (lane & 15);
  int kb = ks * 32 + ((lane >> 4) << 3);
  bf16x8 o;
#pragma unroll
  for (int j = 0; j < 8; ++j) {
    int k = kb + j;
    float v = (k < DIM) ? Wl[k * DIM + c] : Wr[(k - DIM) * DIM + c];
    o[j] = (short)f2bf(v);
  }
  reinterpret_cast<bf16x8*>(Bpack)[(ks * 8 + nt) * 64 + lane] = o;
}

// ---------------------------------------------------------------------------
// K7: MFMA GEMM + fused bias/relu/row-masked column-sum -> per-wave partials
// ---------------------------------------------------------------------------
__global__ __launch_bounds__(256) void mfma_kernel(
    const short* __restrict__ A, const short* __restrict__ Bpack,
    const float* __restrict__ bl, float* __restrict__ partial, int nnodes) {
  __shared__ short a_lds[64 * 256];
  const int tid = threadIdx.x;
  const int wave = tid >> 6, lane = tid & 63;
  const int mt = blockIdx.x;
  const size_t abase = (size_t)mt * 64 * 256;

#pragma unroll
  for (int r = 0; r < 8; ++r) {
    int i = tid + 256 * r;
    int row = i >> 5, kc = i & 31;
    bf16x8 v = *reinterpret_cast<const bf16x8*>(A + abase + row * 256 + kc * 8);
    int byte = (row * 512 + kc * 16) ^ ((row & 7) << 4);
    *reinterpret_cast<bf16x8*>(reinterpret_cast<char*>(a_lds) + byte) = v;
  }
  __syncthreads();

  f32x4 acc[8];
#pragma unroll
  for (int nt = 0; nt < 8; ++nt) acc[nt] = (f32x4){0.f, 0.f, 0.f, 0.f};

  const int arow = wave * 16 + (lane & 15);
  const int kgrp = lane >> 4;
  const bf16x8* Bp = reinterpret_cast<const bf16x8*>(Bpack);

#pragma unroll
  for (int ks = 0; ks < 8; ++ks) {
    int byte = (arow * 512 + (ks * 32 + kgrp * 8) * 2) ^ ((arow & 7) << 4);
    bf16x8 a = *reinterpret_cast<const bf16x8*>(reinterpret_cast<char*>(a_lds) + byte);
#pragma unroll
    for (int nt = 0; nt < 8; ++nt) {
      bf16x8 b = Bp[(ks * 8 + nt) * 64 + lane];
      acc[nt] = __builtin_amdgcn_mfma_f32_16x16x32_bf16(a, b, acc[nt], 0, 0, 0);
    }
  }

  const int col16 = lane & 15;
  const int rowbase = mt * 64 + wave * 16 + kgrp * 4;
#pragma unroll
  for (int nt = 0; nt < 8; ++nt) {
    const int c = nt * 16 + col16;
    const float bb = bl[c];
    float s = 0.f;
#pragma unroll
    for (int rg = 0; rg < 4; ++rg) {
      float v = fmaxf(acc[nt][rg] + bb, 0.f);
      s += (rowbase + rg < nnodes) ? v : 0.f;
    }
    s += __shfl_xor(s, 16);
    s += __shfl_xor(s, 32);
    if (kgrp == 0) partial[((size_t)mt * 4 + wave) * DIM + c] = s;
  }
}

// ---------------------------------------------------------------------------
// K8a: parallel row-reduction of partial [nrows][128] -> red[128][128].
// 128 blocks; block b sums a contiguous chunk of rows (coalesced 512B reads,
// two rows in flight via the two 128-thread halves).
// ---------------------------------------------------------------------------
__global__ __launch_bounds__(256) void red1_kernel(
    const float* __restrict__ partial, int nrows, float* __restrict__ red) {
  __shared__ float tmp[128];
  const int c = threadIdx.x & 127;
  const int half = threadIdx.x >> 7;
  const int chunk = (nrows + 127) / 128;
  const int r0 = blockIdx.x * chunk;
  const int r1 = min(r0 + chunk, nrows);
  float s = 0.f;
  for (int r = r0 + half; r < r1; r += 2) s += partial[(size_t)r * DIM + c];
  if (half) tmp[c] = s;
  __syncthreads();
  if (!half) red[(size_t)blockIdx.x * DIM + c] = s + tmp[c];
}

// ---------------------------------------------------------------------------
// K8b: sum red's 128 rows, dot with W_out, scale, add bias.
// ---------------------------------------------------------------------------
__global__ __launch_bounds__(256) void red2_kernel(
    const float* __restrict__ red, const float* __restrict__ Wout,
    const float* __restrict__ bout, float* __restrict__ out, int nnodes) {
  __shared__ float tmp[128];
  __shared__ float prod[128];
  const int c = threadIdx.x & 127;
  const int half = threadIdx.x >> 7;
  float s = 0.f;
  for (int r = half; r < 128; r += 2) s += red[(size_t)r * DIM + c];
  if (half) tmp[c] = s;
  __syncthreads();
  if (!half) prod[c] = (s + tmp[c]) * Wout[c];
  __syncthreads();
  if (threadIdx.x == 0) {
    float v = 0.f;
    for (int i = 0; i < 128; ++i) v += prod[i];
    out[0] = v / (float)nnodes + bout[0];
  }
}

extern "C" void kernel_launch(void* const* d_in, const int* in_sizes, int n_in,
                              void* d_out, int out_size, void* d_ws, size_t ws_size,
                              hipStream_t stream) {
  const float* x    = (const float*)d_in[0];   // x_ligand [N,128]
  const int*   ei   = (const int*)d_in[4];     // ei_ll [2,E]
  const float* Wl   = (const float*)d_in[11];  // Wl_ll [128,128]
  const float* bl   = (const float*)d_in[12];  // bl_ll [128]
  const float* Wr   = (const float*)d_in[13];  // Wr_ll [128,128]
  const float* Wout = (const float*)d_in[14];  // W_out [128,1]
  const float* bout = (const float*)d_in[15];  // b_out [1]

  const int nnodes = in_sizes[0] / DIM;
  const int E = in_sizes[4] / 2;
  const int mtiles = (nnodes + 63) / 64;
  const int mpad = mtiles * 64;

  // ws layout: [cnt N][fillc N][off N][scratch N][bsum 256][bucket E]
  //            [A mpad*256 bf16][Bpack 32768 bf16][red 128*128 f32]
  // partial (mtiles*4*128 f32) aliases bucket (dead after agg_kernel).
  int* cnt_i   = (int*)d_ws;
  int* fillc   = cnt_i + nnodes;
  int* off     = fillc + nnodes;
  int* scratch = off + nnodes;
  int* bsum    = scratch + nnodes;
  int* bucket  = bsum + 256;
  short* A     = (short*)(bucket + E);
  short* Bpack = A + (size_t)mpad * 256;
  float* red   = (float*)(Bpack + 32768);
  float* partial = (float*)bucket;  // alias

  hipMemsetAsync(d_ws, 0, (size_t)(2 * nnodes) * sizeof(int), stream);

  const int eblocks = (E + 255) / 256;
  hist_kernel<<<eblocks, 256, 0, stream>>>(ei, cnt_i, E);

  const int nblocks = (nnodes + 255) / 256;
  scan1_kernel<<<nblocks, 256, 0, stream>>>(cnt_i, scratch, bsum, nnodes);
  scan2_kernel<<<1, 256, 0, stream>>>(bsum, nblocks);
  scan3_kernel<<<nblocks, 256, 0, stream>>>(scratch, bsum, off, nnodes);

  fill_kernel<<<eblocks, 256, 0, stream>>>(ei, off, fillc, bucket, E);

  bpack_kernel<<<16, 256, 0, stream>>>(Wl, Wr, Bpack);

  const int xblocks = (mpad * 32 + 255) / 256;
  xcast_kernel<<<xblocks, 256, 0, stream>>>(x, A, nnodes, mpad);

  const int ablocks = (mpad + 3) / 4;  // one wave per node
  agg_kernel<<<ablocks, 256, 0, stream>>>(cnt_i, off, bucket, A, nnodes, mpad);

  mfma_kernel<<<mtiles, 256, 0, stream>>>(A, Bpack, bl, partial, nnodes);

  red1_kernel<<<128, 256, 0, stream>>>(partial, mtiles * 4, red);
  red2_kernel<<<1, 256, 0, stream>>>(red, Wout, bout, (float*)d_out, nnodes);
}